// Round 7
// baseline (2086.174 us; speedup 1.0000x reference)
//
#include <hip/hip_runtime.h>
#include <hip/hip_fp16.h>

#define B_ 256
#define T_ 1200
#define I_ 16
#define H_ 128

typedef __attribute__((ext_vector_type(2))) _Float16 h2;
typedef __attribute__((ext_vector_type(8))) _Float16 f16x8;

#if __has_builtin(__builtin_amdgcn_fdot2)
__device__ __forceinline__ float fdot2(h2 a, h2 b, float c) {
  return __builtin_amdgcn_fdot2(a, b, c, false);  // v_dot2_f32_f16
}
#else
__device__ __forceinline__ float fdot2(h2 a, h2 b, float c) {
  return fmaf((float)a.x, (float)b.x, fmaf((float)a.y, (float)b.y, c));
}
#endif

__device__ __forceinline__ float qsum(float x) {
  // sum across the 4 lanes of a quad via DPP quad_perm (VALU pipe)
  x += __int_as_float(__builtin_amdgcn_update_dpp(0, __float_as_int(x), 0xB1, 0xF, 0xF, true)); // xor 1
  x += __int_as_float(__builtin_amdgcn_update_dpp(0, __float_as_int(x), 0x4E, 0xF, 0xF, true)); // xor 2
  return x;
}

__device__ __forceinline__ float sigm(float x) {
  return __builtin_amdgcn_rcpf(1.f + __expf(-x));
}
__device__ __forceinline__ float tanh_(float x) {
  return 1.f - 2.f * __builtin_amdgcn_rcpf(1.f + __expf(2.f * x));
}

// --- named-scalar weight storage: NO arrays -> no alloca -> no scratch ---
// NOTE: "p##0 .x" (with space) — "0.x" would otherwise lex as one pp-number
// token and break the paste (round-6 compile failure).
#define DECL16(p) h2 p##0,p##1,p##2,p##3,p##4,p##5,p##6,p##7,p##8,p##9,p##10,p##11,p##12,p##13,p##14,p##15;

#define LOADROW(p, src) { \
  const float4 v0_ = *(const float4*)((src) + 0); \
  const float4 v1_ = *(const float4*)((src) + 4); \
  const float4 v2_ = *(const float4*)((src) + 8); \
  const float4 v3_ = *(const float4*)((src) + 12); \
  const float4 v4_ = *(const float4*)((src) + 16); \
  const float4 v5_ = *(const float4*)((src) + 20); \
  const float4 v6_ = *(const float4*)((src) + 24); \
  const float4 v7_ = *(const float4*)((src) + 28); \
  p##0 .x=(_Float16)v0_.x;  p##0 .y=(_Float16)v0_.y;  p##1 .x=(_Float16)v0_.z;  p##1 .y=(_Float16)v0_.w; \
  p##2 .x=(_Float16)v1_.x;  p##2 .y=(_Float16)v1_.y;  p##3 .x=(_Float16)v1_.z;  p##3 .y=(_Float16)v1_.w; \
  p##4 .x=(_Float16)v2_.x;  p##4 .y=(_Float16)v2_.y;  p##5 .x=(_Float16)v2_.z;  p##5 .y=(_Float16)v2_.w; \
  p##6 .x=(_Float16)v3_.x;  p##6 .y=(_Float16)v3_.y;  p##7 .x=(_Float16)v3_.z;  p##7 .y=(_Float16)v3_.w; \
  p##8 .x=(_Float16)v4_.x;  p##8 .y=(_Float16)v4_.y;  p##9 .x=(_Float16)v4_.z;  p##9 .y=(_Float16)v4_.w; \
  p##10 .x=(_Float16)v5_.x; p##10 .y=(_Float16)v5_.y; p##11 .x=(_Float16)v5_.z; p##11 .y=(_Float16)v5_.w; \
  p##12 .x=(_Float16)v6_.x; p##12 .y=(_Float16)v6_.y; p##13 .x=(_Float16)v6_.z; p##13 .y=(_Float16)v6_.w; \
  p##14 .x=(_Float16)v7_.x; p##14 .y=(_Float16)v7_.y; p##15 .x=(_Float16)v7_.z; p##15 .y=(_Float16)v7_.w; }

// h2 from constant lanes of an f16x8 (pure extract/insertelement, no memory)
#define H2AT(f, a, b) ({ h2 t_; t_.x = (f)[a]; t_.y = (f)[b]; t_; })

// accumulate 8 k-elems (one f16x8 LDS chunk) into the 4 gate accumulators
#define GDOT(mat, k0, k1, k2, k3, f) \
  a0 = fdot2(mat##_0_##k0, H2AT(f,0,1), a0); \
  a0 = fdot2(mat##_0_##k1, H2AT(f,2,3), a0); \
  a0 = fdot2(mat##_0_##k2, H2AT(f,4,5), a0); \
  a0 = fdot2(mat##_0_##k3, H2AT(f,6,7), a0); \
  a1 = fdot2(mat##_1_##k0, H2AT(f,0,1), a1); \
  a1 = fdot2(mat##_1_##k1, H2AT(f,2,3), a1); \
  a1 = fdot2(mat##_1_##k2, H2AT(f,4,5), a1); \
  a1 = fdot2(mat##_1_##k3, H2AT(f,6,7), a1); \
  a2 = fdot2(mat##_2_##k0, H2AT(f,0,1), a2); \
  a2 = fdot2(mat##_2_##k1, H2AT(f,2,3), a2); \
  a2 = fdot2(mat##_2_##k2, H2AT(f,4,5), a2); \
  a2 = fdot2(mat##_2_##k3, H2AT(f,6,7), a2); \
  a3 = fdot2(mat##_3_##k0, H2AT(f,0,1), a3); \
  a3 = fdot2(mat##_3_##k1, H2AT(f,2,3), a3); \
  a3 = fdot2(mat##_3_##k2, H2AT(f,4,5), a3); \
  a3 = fdot2(mat##_3_##k3, H2AT(f,6,7), a3);

// all 4 chunks (32 k-elems) of one matrix against an LDS h-vector
#define MATDOT(mat, base) { \
  { const f16x8 f_ = *(const f16x8*)((base) + 0);  GDOT(mat, 0, 1, 2, 3,  f_) } \
  { const f16x8 f_ = *(const f16x8*)((base) + 8);  GDOT(mat, 4, 5, 6, 7,  f_) } \
  { const f16x8 f_ = *(const f16x8*)((base) + 16); GDOT(mat, 8, 9, 10,11, f_) } \
  { const f16x8 f_ = *(const f16x8*)((base) + 24); GDOT(mat, 12,13,14,15, f_) } }

// Fully fused 2-layer LSTM + linear head. One WG (512 thr) per batch row.
// Quad owns h-index j (j = tid>>2); lane c = tid&3 holds k-slice [32c,32c+32)
// of W_hh0, W_ih1, W_hh1 rows {j, j+128, j+256, j+384} as 192 NAMED h2
// scalars (SSA -> guaranteed VGPR residency; R5's arrays were left in
// scratch by SROA -> L2-bound reloads). 512 thr = 8 waves = 2/SIMD; with
// waves_per_eu(2,2) the budget is 512/2 = 256 VGPRs.
__global__ __launch_bounds__(512)
__attribute__((amdgpu_waves_per_eu(2, 2)))
void lstm_fused(
    const float* __restrict__ xin,
    const float* __restrict__ Wih0, const float* __restrict__ Whh0,
    const float* __restrict__ bih0, const float* __restrict__ bhh0,
    const float* __restrict__ Wih1, const float* __restrict__ Whh1,
    const float* __restrict__ bih1, const float* __restrict__ bhh1,
    const float* __restrict__ Wlin, const float* __restrict__ blin,
    float* __restrict__ out)
{
  __shared__ __align__(16) __half buf0[2][H_];   // layer-0 h, double buffered
  __shared__ __align__(16) __half buf1[2][H_];   // layer-1 h
  __shared__ __align__(16) float red[2][8];      // out-reduction per wave

  const int tid = threadIdx.x;
  const int c = tid & 3;
  const int j = tid >> 2;
  const int b = blockIdx.x;
  const int wv = tid >> 6;

  DECL16(w0_0_) DECL16(w0_1_) DECL16(w0_2_) DECL16(w0_3_)   // W_hh0
  DECL16(wi_0_) DECL16(wi_1_) DECL16(wi_2_) DECL16(wi_3_)   // W_ih1
  DECL16(wh_0_) DECL16(wh_1_) DECL16(wh_2_) DECL16(wh_3_)   // W_hh1

  const int co = c * 32;
  LOADROW(w0_0_, Whh0 + (size_t)(0 * H_ + j) * H_ + co)
  LOADROW(w0_1_, Whh0 + (size_t)(1 * H_ + j) * H_ + co)
  LOADROW(w0_2_, Whh0 + (size_t)(2 * H_ + j) * H_ + co)
  LOADROW(w0_3_, Whh0 + (size_t)(3 * H_ + j) * H_ + co)
  LOADROW(wi_0_, Wih1 + (size_t)(0 * H_ + j) * H_ + co)
  LOADROW(wi_1_, Wih1 + (size_t)(1 * H_ + j) * H_ + co)
  LOADROW(wi_2_, Wih1 + (size_t)(2 * H_ + j) * H_ + co)
  LOADROW(wi_3_, Wih1 + (size_t)(3 * H_ + j) * H_ + co)
  LOADROW(wh_0_, Whh1 + (size_t)(0 * H_ + j) * H_ + co)
  LOADROW(wh_1_, Whh1 + (size_t)(1 * H_ + j) * H_ + co)
  LOADROW(wh_2_, Whh1 + (size_t)(2 * H_ + j) * H_ + co)
  LOADROW(wh_3_, Whh1 + (size_t)(3 * H_ + j) * H_ + co)

  // W_ih0 slice (K=16): 2 h2 per gate
  h2 wx00, wx01, wx10, wx11, wx20, wx21, wx30, wx31;
  {
    const float4 v0 = *(const float4*)(Wih0 + (size_t)(0 * H_ + j) * I_ + 4 * c);
    const float4 v1 = *(const float4*)(Wih0 + (size_t)(1 * H_ + j) * I_ + 4 * c);
    const float4 v2 = *(const float4*)(Wih0 + (size_t)(2 * H_ + j) * I_ + 4 * c);
    const float4 v3 = *(const float4*)(Wih0 + (size_t)(3 * H_ + j) * I_ + 4 * c);
    wx00.x=(_Float16)v0.x; wx00.y=(_Float16)v0.y; wx01.x=(_Float16)v0.z; wx01.y=(_Float16)v0.w;
    wx10.x=(_Float16)v1.x; wx10.y=(_Float16)v1.y; wx11.x=(_Float16)v1.z; wx11.y=(_Float16)v1.w;
    wx20.x=(_Float16)v2.x; wx20.y=(_Float16)v2.y; wx21.x=(_Float16)v2.z; wx21.y=(_Float16)v2.w;
    wx30.x=(_Float16)v3.x; wx30.y=(_Float16)v3.y; wx31.x=(_Float16)v3.z; wx31.y=(_Float16)v3.w;
  }
  const float bs0_0 = bih0[0*H_+j] + bhh0[0*H_+j];
  const float bs0_1 = bih0[1*H_+j] + bhh0[1*H_+j];
  const float bs0_2 = bih0[2*H_+j] + bhh0[2*H_+j];
  const float bs0_3 = bih0[3*H_+j] + bhh0[3*H_+j];
  const float bs1_0 = bih1[0*H_+j] + bhh1[0*H_+j];
  const float bs1_1 = bih1[1*H_+j] + bhh1[1*H_+j];
  const float bs1_2 = bih1[2*H_+j] + bhh1[2*H_+j];
  const float bs1_3 = bih1[3*H_+j] + bhh1[3*H_+j];

  const float wl4 = Wlin[j] * 0.25f;  // quad holds j 4x redundant -> /4
  const float bl = blin[0];

  if (tid < H_) {
    buf0[0][tid] = __float2half(0.f);
    buf1[0][tid] = __float2half(0.f);
  }
  float cst0 = 0.f, cst1 = 0.f;
  const float* xp = xin + (size_t)b * T_ * I_ + 4 * c;
  float* op = out + (size_t)b * T_;
  float4 xv_next = *(const float4*)xp;  // software-pipelined x prefetch
  __syncthreads();

#pragma unroll 2
  for (int t = 0; t < T_; ++t) {
    const int rb = t & 1;
    // ---------------- layer 0 ----------------
    const float4 xv = xv_next;
    xp += I_;
    if (t + 1 < T_) xv_next = *(const float4*)xp;  // prefetch next step's x
    float a0 = 0.f, a1 = 0.f, a2 = 0.f, a3 = 0.f;
    MATDOT(w0, &buf0[rb][co])
    {
      h2 xa, xb;
      xa.x = (_Float16)xv.x; xa.y = (_Float16)xv.y;
      xb.x = (_Float16)xv.z; xb.y = (_Float16)xv.w;
      a0 = fdot2(wx00, xa, fdot2(wx01, xb, a0));
      a1 = fdot2(wx10, xa, fdot2(wx11, xb, a1));
      a2 = fdot2(wx20, xa, fdot2(wx21, xb, a2));
      a3 = fdot2(wx30, xa, fdot2(wx31, xb, a3));
      const float g0 = qsum(a0) + bs0_0;
      const float g1 = qsum(a1) + bs0_1;
      const float g2 = qsum(a2) + bs0_2;
      const float g3 = qsum(a3) + bs0_3;
      const float ig = sigm(g0), fg = sigm(g1), gg = tanh_(g2), og = sigm(g3);
      cst0 = fg * cst0 + ig * gg;
      const float h0v = og * tanh_(cst0);
      if (c == 0) buf0[rb ^ 1][j] = __float2half(h0v);
    }
    __syncthreads();
    // ---------------- layer 1 ----------------
    a0 = 0.f; a1 = 0.f; a2 = 0.f; a3 = 0.f;
    MATDOT(wi, &buf0[rb ^ 1][co])   // h0_t
    MATDOT(wh, &buf1[rb][co])       // h1_{t-1}
    const float g0 = qsum(a0) + bs1_0;
    const float g1 = qsum(a1) + bs1_1;
    const float g2 = qsum(a2) + bs1_2;
    const float g3 = qsum(a3) + bs1_3;
    const float ig = sigm(g0), fg = sigm(g1), gg = tanh_(g2), og = sigm(g3);
    cst1 = fg * cst1 + ig * gg;
    const float h1v = og * tanh_(cst1);
    if (c == 0) buf1[rb ^ 1][j] = __float2half(h1v);
    // fused relu + W_lin dot: sum over all 512 threads (each j 4x -> wl4)
    float val = fmaxf(h1v, 0.f) * wl4;
    val += __shfl_xor(val, 1);
    val += __shfl_xor(val, 2);
    val += __shfl_xor(val, 4);
    val += __shfl_xor(val, 8);
    val += __shfl_xor(val, 16);
    val += __shfl_xor(val, 32);
    if ((tid & 63) == 0) red[rb][wv] = val;
    __syncthreads();
    // rotate the storing wave to avoid a fixed straggler; red[rb] is not
    // rewritten until t+2, which is >=3 barriers after this read.
    if (tid == ((t & 7) << 6)) {
      const float4 r0 = *(const float4*)(&red[rb][0]);
      const float4 r1 = *(const float4*)(&red[rb][4]);
      op[t] = bl + r0.x + r0.y + r0.z + r0.w + r1.x + r1.y + r1.z + r1.w;
    }
  }
}

extern "C" void kernel_launch(void* const* d_in, const int* in_sizes, int n_in,
                              void* d_out, int out_size, void* d_ws, size_t ws_size,
                              hipStream_t stream) {
  // Zero-workspace design: d_ws deliberately unused.
  lstm_fused<<<B_, 512, 0, stream>>>(
      (const float*)d_in[0],
      (const float*)d_in[1], (const float*)d_in[2],
      (const float*)d_in[3], (const float*)d_in[4],
      (const float*)d_in[5], (const float*)d_in[6],
      (const float*)d_in[7], (const float*)d_in[8],
      (const float*)d_in[9], (const float*)d_in[10],
      (float*)d_out);
}